// Round 9
// baseline (64150.995 us; speedup 1.0000x reference)
//
#include <hip/hip_runtime.h>

#define NB 64      // batch
#define NL 512     // seq len
#define NT 64      // answer len
#define NH 512     // hidden
#define NE 256     // emb dim
#define NW 256     // attention weight dim
#define PAD 520    // LDS row stride (u16) for h tiles: 512+8 breaks bank alias

typedef __attribute__((ext_vector_type(8))) short bf16x8;
typedef __attribute__((ext_vector_type(4))) float f32x4;
typedef unsigned short u16;
typedef unsigned int u32;

__device__ __forceinline__ float bf2f(u16 v){
  union { u32 u; float f; } x; x.u = ((u32)v) << 16; return x.f;
}
__device__ __forceinline__ u16 f2bf(float f){
  union { float f; u32 u; } x; x.f = f;
  return (u16)((x.u + 0x7FFFu + ((x.u >> 16) & 1u)) >> 16);
}
__device__ __forceinline__ float sigm(float x){ return 1.f / (1.f + __expf(-x)); }
__device__ __forceinline__ float tanh_(float x){ float e = __expf(2.f * x); return 1.f - 2.f / (e + 1.f); }

// fp32 -> bf16 (round-to-nearest-even)
__global__ void cvt_kernel(const float* __restrict__ src, u16* __restrict__ dst, int n){
  const int i = blockIdx.x * 256 + threadIdx.x;
  if(i < n) dst[i] = f2bf(src[i]);
}

// ---------------------------------------------------------------------------
// Encoder: 4 FULLY INDEPENDENT blocks (one per 16-row batch tile), 512
// threads = 8 waves. The LSTM recurrence is batch-row independent, so h never
// leaves the block: it lives in a 2-slot LDS buffer, one __syncthreads/step.
// Wave w owns j-tiles jt = w*4+q (q=0..3) x 4 gates = 16 MFMA output tiles.
// Cell state c in registers. blend1[t] = h_t @ W1^T + b1 folded in per step.
// h_511 written to global for the decoder's c0 (kernel-boundary ordered).
// Zero cross-workgroup communication.
// ---------------------------------------------------------------------------
__global__ void __launch_bounds__(512, 2) enc_kernel(
    const int* __restrict__ ids, const u16* __restrict__ emb,
    const u16* __restrict__ Wih, const u16* __restrict__ Whh,
    const float* __restrict__ bih, const float* __restrict__ bhh,
    const u16* __restrict__ W1,  const float* __restrict__ b1,
    u16* __restrict__ bl, u16* __restrict__ h511g)
{
  __shared__ u16 hlds[2][16][PAD];

  const int tid  = threadIdx.x;
  const int lane = tid & 63;
  const int wvl  = tid >> 6;        // 0..7
  const int col  = lane & 15;
  const int quad = lane >> 4;
  const int btile = blockIdx.x;     // 0..3

  // 16 tiles: (q = jt offset, g = gate). Precompute biases + row pointers.
  float bias[4][4];
  const u16* wh[4][4];
  const u16* wx[4][4];
#pragma unroll
  for(int q = 0; q < 4; ++q){
    const int j = (wvl * 4 + q) * 16 + col;
#pragma unroll
    for(int g = 0; g < 4; ++g){
      const int row = g * NH + j;   // PyTorch gate order i,f,g,o
      bias[q][g] = bih[row] + bhh[row];
      wh[q][g] = Whh + (size_t)row * NH + quad * 8;
      wx[q][g] = Wih + (size_t)row * NE + quad * 8;
    }
  }
  const int* idp = ids + (btile * 16 + col) * NL;   // A-row (batch) per lane
  // blend fold: wave owns n-tiles wvl*2, wvl*2+1
  const u16* w1p[2];
  float b1f[2];
#pragma unroll
  for(int u = 0; u < 2; ++u){
    const int n = (wvl * 2 + u) * 16 + col;
    w1p[u] = W1 + (size_t)n * NH + quad * 8;
    b1f[u] = b1[n];
  }
  float creg[4][4];                 // cell state: [q][r], lane-owned
#pragma unroll
  for(int q = 0; q < 4; ++q)
#pragma unroll
    for(int r = 0; r < 4; ++r) creg[q][r] = 0.f;

  for(int t = 0; t < NL; ++t){
    f32x4 acc[4][4];
#pragma unroll
    for(int q = 0; q < 4; ++q)
#pragma unroll
      for(int g = 0; g < 4; ++g) acc[q][g] = (f32x4){0.f, 0.f, 0.f, 0.f};

    // x part: A row = emb[ids[batch_row, t]]  (K = 256)
    {
      const u16* xr = emb + (size_t)idp[t] * NE + quad * 8;
#pragma unroll
      for(int i = 0; i < 8; ++i){
        const bf16x8 af = *(const bf16x8*)(xr + i * 32);
#pragma unroll
        for(int q = 0; q < 4; ++q)
#pragma unroll
          for(int g = 0; g < 4; ++g)
            acc[q][g] = __builtin_amdgcn_mfma_f32_16x16x32_bf16(af, *(const bf16x8*)(wx[q][g] + i * 32), acc[q][g], 0, 0, 0);
      }
    }
    // h part from LDS (h_{-1}=0 -> skip at t=0)  (K = 512)
    if(t > 0){
      const u16* hp = &hlds[(t + 1) & 1][0][0] + col * PAD + quad * 8;
#pragma unroll
      for(int i = 0; i < 16; ++i){
        const bf16x8 af = *(const bf16x8*)(hp + i * 32);
#pragma unroll
        for(int q = 0; q < 4; ++q)
#pragma unroll
          for(int g = 0; g < 4; ++g)
            acc[q][g] = __builtin_amdgcn_mfma_f32_16x16x32_bf16(af, *(const bf16x8*)(wh[q][g] + i * 32), acc[q][g], 0, 0, 0);
      }
    }
    // epilogue: cell update in registers, h_t -> LDS slot t&1
    u16* hc = &hlds[t & 1][0][0];
#pragma unroll
    for(int q = 0; q < 4; ++q){
      const int j = (wvl * 4 + q) * 16 + col;
#pragma unroll
      for(int r = 0; r < 4; ++r){
        const int row = quad * 4 + r;            // batch row within tile
        const float gi = acc[q][0][r] + bias[q][0];
        const float gf = acc[q][1][r] + bias[q][1];
        const float gg = acc[q][2][r] + bias[q][2];
        const float go = acc[q][3][r] + bias[q][3];
        creg[q][r] = sigm(gf) * creg[q][r] + sigm(gi) * tanh_(gg);
        const u16 hv = f2bf(sigm(go) * tanh_(creg[q][r]));
        hc[row * PAD + j] = hv;
        if(t == NL - 1)
          h511g[(size_t)(btile * 16 + row) * NH + j] = hv;
      }
    }
    __syncthreads();   // h_t complete in LDS (also licenses next-step reads)

    // blend1[t] fold: A = h_t rows (batch), B = W1 rows (n)
    {
      f32x4 a2[2] = {(f32x4){0.f,0.f,0.f,0.f}, (f32x4){0.f,0.f,0.f,0.f}};
      const u16* hp = hc + col * PAD + quad * 8;
#pragma unroll
      for(int i = 0; i < 16; ++i){
        const bf16x8 af = *(const bf16x8*)(hp + i * 32);
#pragma unroll
        for(int u = 0; u < 2; ++u)
          a2[u] = __builtin_amdgcn_mfma_f32_16x16x32_bf16(af, *(const bf16x8*)(w1p[u] + i * 32), a2[u], 0, 0, 0);
      }
#pragma unroll
      for(int u = 0; u < 2; ++u){
        const int n = (wvl * 2 + u) * 16 + col;
#pragma unroll
        for(int r = 0; r < 4; ++r){
          const int b = btile * 16 + quad * 4 + r;
          bl[((size_t)t * NB + b) * NW + n] = f2bf(a2[u][r] + b1f[u]);
        }
      }
    }
  }
}

// ---------------------------------------------------------------------------
// Decoder: 64 FULLY INDEPENDENT blocks (one per batch column), 256 threads.
// The decoder LSTM is also batch-row independent: block b runs the row-b
// recurrence locally (h broadcast from LDS into MFMA A operand, gates ->
// LDS), then does attention + log-softmax for column b. c0 = h511g[b,:],
// h_{-1} = h0[b,:]. Zero cross-workgroup communication.
// ---------------------------------------------------------------------------
__global__ void __launch_bounds__(256, 1) dec_kernel(
    const u16* __restrict__ Whh, const float* __restrict__ bih, const float* __restrict__ bhh,
    const u16* __restrict__ W2b, const float* __restrict__ b2,
    const float* __restrict__ vt, const float* __restrict__ vtb,
    const u16* __restrict__ bl,  const u16* __restrict__ h511g,
    const float* __restrict__ h0f, float* __restrict__ out)
{
  __shared__ u16  hbuf[2][NH];
  __shared__ float gates[4 * NH];   // 8 KB
  __shared__ float u_lds[NW];
  __shared__ float vt_lds[NW];
  __shared__ float s_lds[NL];
  __shared__ float red[8];

  const int tid  = threadIdx.x;
  const int lane = tid & 63;
  const int wvl  = tid >> 6;        // 0..3
  const int col  = lane & 15;
  const int quad = lane >> 4;
  const int myb  = blockIdx.x;

  // thread owns hidden j = tid and j2 = tid+256 for the cell update
  float bia0[4], bia1[4];
#pragma unroll
  for(int g = 0; g < 4; ++g){
    bia0[g] = bih[g * NH + tid]       + bhh[g * NH + tid];
    bia1[g] = bih[g * NH + tid + 256] + bhh[g * NH + tid + 256];
  }
  float c0 = bf2f(h511g[(size_t)myb * NH + tid]);        // c init = enc h_511
  float c1 = bf2f(h511g[(size_t)myb * NH + tid + 256]);
  hbuf[1][tid]       = f2bf(h0f[(size_t)myb * NH + tid]);        // h_{-1} = h0
  hbuf[1][tid + 256] = f2bf(h0f[(size_t)myb * NH + tid + 256]);
  vt_lds[tid] = vt[tid];
  const float vtbf = vtb[0];
  const u16* w2r = W2b + (size_t)tid * NH;
  const float b2f = b2[tid];
  __syncthreads();

  for(int t = 0; t < NT; ++t){
    // ---- LSTM gates via MFMA: A = broadcast h_{t-1}, B = Whh rows ----
    {
      const u16* hp = hbuf[(t + 1) & 1] + quad * 8;
      for(int nt0 = wvl * 32; nt0 < wvl * 32 + 32; nt0 += 4){
        f32x4 ac[4];
#pragma unroll
        for(int u = 0; u < 4; ++u) ac[u] = (f32x4){0.f, 0.f, 0.f, 0.f};
#pragma unroll
        for(int i = 0; i < 16; ++i){
          const bf16x8 af = *(const bf16x8*)(hp + i * 32);   // LDS broadcast
#pragma unroll
          for(int u = 0; u < 4; ++u){
            const u16* bp = Whh + (size_t)((nt0 + u) * 16 + col) * NH + quad * 8 + i * 32;
            ac[u] = __builtin_amdgcn_mfma_f32_16x16x32_bf16(af, *(const bf16x8*)bp, ac[u], 0, 0, 0);
          }
        }
        if(quad == 0){
#pragma unroll
          for(int u = 0; u < 4; ++u) gates[(nt0 + u) * 16 + col] = ac[u][0];
        }
      }
    }
    __syncthreads();
    // ---- cell update: thread tid handles j = tid, tid+256 ----
    {
      u16* hc = hbuf[t & 1];
      {
        const int j = tid;
        const float gi = gates[j] + bia0[0];
        const float gf = gates[NH + j] + bia0[1];
        const float gg = gates[2 * NH + j] + bia0[2];
        const float go = gates[3 * NH + j] + bia0[3];
        c0 = sigm(gf) * c0 + sigm(gi) * tanh_(gg);
        hc[j] = f2bf(sigm(go) * tanh_(c0));
      }
      {
        const int j = tid + 256;
        const float gi = gates[j] + bia1[0];
        const float gf = gates[NH + j] + bia1[1];
        const float gg = gates[2 * NH + j] + bia1[2];
        const float go = gates[3 * NH + j] + bia1[3];
        c1 = sigm(gf) * c1 + sigm(gi) * tanh_(gg);
        hc[j] = f2bf(sigm(go) * tanh_(c1));
      }
    }
    __syncthreads();
    // ---- u[n] = b2[n] + h_t . W2[n,:] ----
    {
      const u16* hr = hbuf[t & 1];
      float s = b2f;
#pragma unroll 4
      for(int k0 = 0; k0 < NH; k0 += 8){
        const bf16x8 hv = *(const bf16x8*)(hr + k0);
        const bf16x8 wv = *(const bf16x8*)(w2r + k0);
#pragma unroll
        for(int e = 0; e < 8; ++e)
          s += bf2f((u16)hv[e]) * bf2f((u16)wv[e]);
      }
      u_lds[tid] = s;
    }
    __syncthreads();
    // ---- scores over L ----
    for(int l = wvl; l < NL; l += 4){
      const u16* br = bl + (size_t)(l * NB + myb) * NW;
      float p = 0.f;
#pragma unroll
      for(int q = 0; q < 4; ++q){
        const int w = lane + 64 * q;
        p += vt_lds[w] * tanh_(bf2f(br[w]) + u_lds[w]);
      }
#pragma unroll
      for(int off = 32; off > 0; off >>= 1) p += __shfl_xor(p, off, 64);
      if(lane == 0) s_lds[l] = p + vtbf;
    }
    __syncthreads();
    // ---- log-softmax over L = 512 ----
    const float a0 = s_lds[tid];
    const float a1 = s_lds[tid + 256];
    float mx = fmaxf(a0, a1);
#pragma unroll
    for(int off = 32; off > 0; off >>= 1) mx = fmaxf(mx, __shfl_xor(mx, off, 64));
    if(lane == 0) red[wvl] = mx;
    __syncthreads();
    mx = fmaxf(fmaxf(red[0], red[1]), fmaxf(red[2], red[3]));
    float es = __expf(a0 - mx) + __expf(a1 - mx);
#pragma unroll
    for(int off = 32; off > 0; off >>= 1) es += __shfl_xor(es, off, 64);
    if(lane == 0) red[4 + wvl] = es;
    __syncthreads();
    const float lse = mx + logf(red[4] + red[5] + red[6] + red[7]);
    out[((size_t)tid * NB + myb) * NT + t]         = a0 - lse;
    out[((size_t)(tid + 256) * NB + myb) * NT + t] = a1 - lse;
    __syncthreads();
  }
}

// ---------------------------------------------------------------------------
extern "C" void kernel_launch(void* const* d_in, const int* in_sizes, int n_in,
                              void* d_out, int out_size, void* d_ws, size_t ws_size,
                              hipStream_t stream)
{
  (void)in_sizes; (void)n_in; (void)out_size; (void)ws_size;
  const int*   ids  = (const int*)d_in[0];
  const float* emb  = (const float*)d_in[1];
  const float* eWih = (const float*)d_in[2];
  const float* eWhh = (const float*)d_in[3];
  const float* ebih = (const float*)d_in[4];
  const float* ebhh = (const float*)d_in[5];
  /* d_in[6] = dec_Wih: unused (decoder input is identically zero) */
  const float* dWhh = (const float*)d_in[7];
  const float* dbih = (const float*)d_in[8];
  const float* dbhh = (const float*)d_in[9];
  const float* W1   = (const float*)d_in[10];
  const float* b1   = (const float*)d_in[11];
  const float* W2   = (const float*)d_in[12];
  const float* b2   = (const float*)d_in[13];
  const float* vt   = (const float*)d_in[14];
  const float* vtb  = (const float*)d_in[15];
  const float* h0   = (const float*)d_in[16];

  // workspace: ~27.8 MB (proven envelope)
  char* ws = (char*)d_ws;
  u16* bl     = (u16*)ws; ws += (size_t)NL * NB * NW * 2;    // blend1 bf16  16.78 MB
  u16* emb_b  = (u16*)ws; ws += (size_t)10000 * NE * 2;      // 5.12 MB
  u16* eWih_b = (u16*)ws; ws += (size_t)4 * NH * NE * 2;     // 1.05 MB
  u16* eWhh_b = (u16*)ws; ws += (size_t)4 * NH * NH * 2;     // 2.10 MB
  u16* dWhh_b = (u16*)ws; ws += (size_t)4 * NH * NH * 2;     // 2.10 MB
  u16* W1_b   = (u16*)ws; ws += (size_t)NW * NH * 2;         // 0.26 MB
  u16* W2_b   = (u16*)ws; ws += (size_t)NW * NH * 2;         // 0.26 MB
  u16* h511g  = (u16*)ws; ws += (size_t)NB * NH * 2;         // 64 KB

  hipLaunchKernelGGL(cvt_kernel, dim3(10000), dim3(256), 0, stream, emb,  emb_b,  10000 * NE);
  hipLaunchKernelGGL(cvt_kernel, dim3(2048), dim3(256), 0, stream, eWih, eWih_b, 4 * NH * NE);
  hipLaunchKernelGGL(cvt_kernel, dim3(4096), dim3(256), 0, stream, eWhh, eWhh_b, 4 * NH * NH);
  hipLaunchKernelGGL(cvt_kernel, dim3(4096), dim3(256), 0, stream, dWhh, dWhh_b, 4 * NH * NH);
  hipLaunchKernelGGL(cvt_kernel, dim3(512),  dim3(256), 0, stream, W1,   W1_b,   NW * NH);
  hipLaunchKernelGGL(cvt_kernel, dim3(512),  dim3(256), 0, stream, W2,   W2_b,   NW * NH);

  hipLaunchKernelGGL(enc_kernel, dim3(4), dim3(512), 0, stream,
                     ids, emb_b, eWih_b, eWhh_b, ebih, ebhh, W1_b, b1, bl, h511g);
  hipLaunchKernelGGL(dec_kernel, dim3(64), dim3(256), 0, stream,
                     dWhh_b, dbih, dbhh, W2_b, b2, vt, vtb, bl, h511g, h0,
                     (float*)d_out);
}

// Round 10
// 7845.296 us; speedup vs baseline: 8.1770x; 8.1770x over previous
//
#include <hip/hip_runtime.h>

#define NB 64      // batch
#define NL 512     // seq len
#define NT 64      // answer len
#define NH 512     // hidden
#define NE 256     // emb dim
#define NW 256     // attention weight dim

typedef __attribute__((ext_vector_type(8))) short bf16x8;
typedef __attribute__((ext_vector_type(4))) float f32x4;
typedef unsigned short u16;
typedef unsigned int u32;
typedef unsigned long long u64;

#define STM 0x4000400040004000ull   // bit14 of each u16 (never set in bf16 of |v|<2)
#define CLRM 0xBFFFBFFFBFFFBFFFull

__device__ __forceinline__ float bf2f(u16 v){
  union { u32 u; float f; } x; x.u = ((u32)v) << 16; return x.f;
}
__device__ __forceinline__ u16 f2bf(float f){
  union { float f; u32 u; } x; x.f = f;
  return (u16)((x.u + 0x7FFFu + ((x.u >> 16) & 1u)) >> 16);
}
__device__ __forceinline__ float sigm(float x){ return 1.f / (1.f + __expf(-x)); }
__device__ __forceinline__ float tanh_(float x){ float e = __expf(2.f * x); return 1.f - 2.f / (e + 1.f); }

// device-scope (L3 coherence point) loads/stores — poll-on-data, no fences
__device__ __forceinline__ u64 ald64(const u64* p){
  return __hip_atomic_load(p, __ATOMIC_RELAXED, __HIP_MEMORY_SCOPE_AGENT);
}
__device__ __forceinline__ void ast64(u64* p, u64 v){
  __hip_atomic_store(p, v, __ATOMIC_RELAXED, __HIP_MEMORY_SCOPE_AGENT);
}
__device__ __forceinline__ bf16x8 mk8(u64 a, u64 b){
  union { u64 q[2]; bf16x8 v; } u; u.q[0] = a; u.q[1] = b; return u.v;
}

__global__ void fill_kernel(u32* p, u32 v){
  p[blockIdx.x * 256 + threadIdx.x] = v;
}

// fp32 -> bf16 (round-to-nearest-even)
__global__ void cvt_kernel(const float* __restrict__ src, u16* __restrict__ dst, int n){
  const int i = blockIdx.x * 256 + threadIdx.x;
  if(i < n) dst[i] = f2bf(src[i]);
}

// ---------------------------------------------------------------------------
// Encoder (R8-proven, 12us/step): 32 blocks x 256 threads, 4 independent
// btile groups of 8 blocks. Wave = 16(batch) x 16(hidden) of all 4 gates;
// cell state in registers; Whh REGISTER-RESIDENT (whr[16][4]) — zero per-step
// L2 weight traffic on the critical path. h in a 2-slot ring; stored u16s are
// stamped in bit14 with parity (t>>1)&1; consumers poll the data itself.
// ---------------------------------------------------------------------------
__global__ void __launch_bounds__(256, 1) enc_kernel(
    const int* __restrict__ ids, const u16* __restrict__ emb,
    const u16* __restrict__ Wih, const u16* __restrict__ Whh,
    const float* __restrict__ bih, const float* __restrict__ bhh,
    const u16* __restrict__ W1,  const float* __restrict__ b1,
    u16* hroll, u16* bl)
{
  const int lane = threadIdx.x & 63;
  const int col  = lane & 15;
  const int quad = lane >> 4;
  const int btile = blockIdx.x & 3;
  const int mtile = (blockIdx.x >> 2) * 4 + (threadIdx.x >> 6);
  const int j  = mtile * 16 + col;        // hidden index within a gate [0,512)
  const int ab = btile * 16 + col;        // A-row (batch) this lane loads

  float bias[4];
  const u16* wx[4];
  bf16x8 whr[16][4];                      // register-resident Whh fragments
#pragma unroll
  for(int g = 0; g < 4; ++g){
    const int row = g * NH + j;           // PyTorch gate order i,f,g,o
    bias[g] = bih[row] + bhh[row];
    wx[g] = Wih + (size_t)row * NE + quad * 8;
    const u16* whp = Whh + (size_t)row * NH + quad * 8;
#pragma unroll
    for(int i = 0; i < 16; ++i)
      whr[i][g] = *(const bf16x8*)(whp + 32 * i);
  }
  const int* idp = ids + ab * NL;         // ids is [B, L]
  const int n1 = mtile * 16 + col;        // blend1 column (mtile<16 only)
  const u16* w1r = W1 + (size_t)(mtile < 16 ? n1 : 0) * NH + quad * 8;
  const float b1f = (mtile < 16) ? b1[n1] : 0.f;
  float creg[4] = {0.f, 0.f, 0.f, 0.f};   // cell state, lane-owned

  u64 hb[32];                             // h_t fragment (stamped-cleaned)
  f32x4 acc[4];

  // x-part of t=0
  {
    const u16* xr = emb + (size_t)idp[0] * NE + quad * 8;
#pragma unroll
    for(int g = 0; g < 4; ++g) acc[g] = (f32x4){0.f, 0.f, 0.f, 0.f};
#pragma unroll
    for(int k0 = 0; k0 < NE; k0 += 32){
      const bf16x8 af = *(const bf16x8*)(xr + k0);
#pragma unroll
      for(int g = 0; g < 4; ++g)
        acc[g] = __builtin_amdgcn_mfma_f32_16x16x32_bf16(af, *(const bf16x8*)(wx[g] + k0), acc[g], 0, 0, 0);
    }
  }

  for(int t = 0; t < NL; ++t){
    // h part (hb = h_{t-1}, loaded by last iteration's poll) — all-register
    if(t > 0){
#pragma unroll
      for(int i = 0; i < 16; ++i){
        const bf16x8 af = mk8(hb[2 * i], hb[2 * i + 1]);
#pragma unroll
        for(int g = 0; g < 4; ++g)
          acc[g] = __builtin_amdgcn_mfma_f32_16x16x32_bf16(af, whr[i][g], acc[g], 0, 0, 0);
      }
    }
    // epilogue: gates -> c (regs); h_t stamped + packed to u64 -> slot t&1
    const u32 st14 = ((u32)((t >> 1) & 1)) << 14;
    u16* ho = hroll + (t & 1) * (NB * NH);
#pragma unroll
    for(int r = 0; r < 4; ++r){
      const float gi = acc[0][r] + bias[0];
      const float gf = acc[1][r] + bias[1];
      const float gg = acc[2][r] + bias[2];
      const float go = acc[3][r] + bias[3];
      creg[r] = sigm(gf) * creg[r] + sigm(gi) * tanh_(gg);
      const u32 stv  = (u32)f2bf(sigm(go) * tanh_(creg[r])) | st14;
      const u32 pair = stv | (((u32)__shfl_xor((int)stv, 1, 64)) << 16);
      const u32 hi   = (u32)__shfl_xor((int)pair, 2, 64);
      if((col & 3) == 0){
        const int row = btile * 16 + quad * 4 + r;
        ast64((u64*)(ho + (size_t)row * NH + mtile * 16 + col),
              (u64)pair | ((u64)hi << 32));
      }
    }
    // overlap: x-part of t+1 while stores become visible
    if(t + 1 < NL){
      const u16* xr = emb + (size_t)idp[t + 1] * NE + quad * 8;
#pragma unroll
      for(int g = 0; g < 4; ++g) acc[g] = (f32x4){0.f, 0.f, 0.f, 0.f};
#pragma unroll
      for(int k0 = 0; k0 < NE; k0 += 32){
        const bf16x8 af = *(const bf16x8*)(xr + k0);
#pragma unroll
        for(int g = 0; g < 4; ++g)
          acc[g] = __builtin_amdgcn_mfma_f32_16x16x32_bf16(af, *(const bf16x8*)(wx[g] + k0), acc[g], 0, 0, 0);
      }
    }
    // poll-on-data: load h_t fragment until every u16 has this step's stamp
    {
      const u16* ha = hroll + (t & 1) * (NB * NH) + (size_t)ab * NH + quad * 8;
      const u64 want = ((t >> 1) & 1) ? STM : 0ull;
      for(;;){
        bool ok = true;
#pragma unroll
        for(int i = 0; i < 16; ++i){
          const u64* p = (const u64*)(ha + 32 * i);
          hb[2 * i]     = ald64(p);
          hb[2 * i + 1] = ald64(p + 1);
          ok = ok && ((hb[2 * i] & STM) == want) && ((hb[2 * i + 1] & STM) == want);
        }
        if(__ballot(ok) == ~0ull) break;
        __builtin_amdgcn_s_sleep(1);
      }
#pragma unroll
      for(int i = 0; i < 32; ++i) hb[i] &= CLRM;
    }
    // blend1[t] fold (normal stores — consumed after kernel boundary)
    if(mtile < 16){
      f32x4 a2 = {0.f, 0.f, 0.f, 0.f};
#pragma unroll
      for(int i = 0; i < 16; ++i)
        a2 = __builtin_amdgcn_mfma_f32_16x16x32_bf16(mk8(hb[2 * i], hb[2 * i + 1]), *(const bf16x8*)(w1r + 32 * i), a2, 0, 0, 0);
#pragma unroll
      for(int r = 0; r < 4; ++r){
        const int b = btile * 16 + quad * 4 + r;
        bl[((size_t)t * NB + b) * NW + n1] = f2bf(a2[r] + b1f);
      }
    }
  }
}

// ---------------------------------------------------------------------------
// Decoder LSTM only (R8's proven producer half): 32 blocks x 256 threads,
// register-resident dWhh, 64 write-once stamped h slots over the dead emb
// region (initial bytes are bf16 emb, |v|<2 => stamp 0). Slot t holds h_t.
// c0 = enc h_511 (hroll slot 1), h_{-1} = fp32 h0. Attention is NOT here —
// it runs afterwards, fully parallel.
// ---------------------------------------------------------------------------
__global__ void __launch_bounds__(256, 1) dec_lstm_kernel(
    const u16* __restrict__ Whh, const float* __restrict__ bih, const float* __restrict__ bhh,
    const u16* __restrict__ hroll, const float* __restrict__ h0f,
    u16* hdX)
{
  const int tid  = threadIdx.x;
  const int lane = tid & 63;
  const int wvl  = tid >> 6;
  const int col  = lane & 15;
  const int quad = lane >> 4;

  const int gw   = blockIdx.x * 4 + wvl;
  const int btile = gw >> 5;
  const int mtile = gw & 31;
  const int j  = mtile * 16 + col;
  const int ab = btile * 16 + col;
  float bias[4];
  bf16x8 whr[16][4];
  float creg[4];
#pragma unroll
  for(int g = 0; g < 4; ++g){
    const int row = g * NH + j;
    bias[g] = bih[row] + bhh[row];
    const u16* whp = Whh + (size_t)row * NH + quad * 8;
#pragma unroll
    for(int i = 0; i < 16; ++i)
      whr[i][g] = *(const bf16x8*)(whp + 32 * i);
  }
  // c0 = enc h_511: hroll slot 511&1 == 1, stamp bit set -> mask it
#pragma unroll
  for(int r = 0; r < 4; ++r){
    const int ci = (btile * 16 + quad * 4 + r) * NH + j;
    creg[r] = bf2f((u16)(hroll[(NB * NH) + ci] & 0xBFFFu));
  }

  for(int t = 0; t < NT; ++t){
    f32x4 z = {0.f, 0.f, 0.f, 0.f};
    f32x4 acc[4] = {z, z, z, z};
    if(t == 0){
      // h_{-1} = h0 (fp32, convert in regs)
      const float* hp = h0f + (size_t)ab * NH + quad * 8;
#pragma unroll
      for(int i = 0; i < 16; ++i){
        const f32x4 a0 = *(const f32x4*)(hp + 32 * i);
        const f32x4 a1 = *(const f32x4*)(hp + 32 * i + 4);
        bf16x8 af;
#pragma unroll
        for(int q = 0; q < 4; ++q){ af[q] = (short)f2bf(a0[q]); af[q + 4] = (short)f2bf(a1[q]); }
#pragma unroll
        for(int g = 0; g < 4; ++g)
          acc[g] = __builtin_amdgcn_mfma_f32_16x16x32_bf16(af, whr[i][g], acc[g], 0, 0, 0);
      }
    } else {
      // poll-on-data: slot t-1 (stamp always 1)
      u64 hb[32];
      const u16* ha = hdX + (size_t)(t - 1) * (NB * NH) + (size_t)ab * NH + quad * 8;
      for(;;){
        bool ok = true;
#pragma unroll
        for(int i = 0; i < 16; ++i){
          const u64* p = (const u64*)(ha + 32 * i);
          hb[2 * i]     = ald64(p);
          hb[2 * i + 1] = ald64(p + 1);
          ok = ok && ((hb[2 * i] & STM) == STM) && ((hb[2 * i + 1] & STM) == STM);
        }
        if(__ballot(ok) == ~0ull) break;
        __builtin_amdgcn_s_sleep(1);
      }
#pragma unroll
      for(int i = 0; i < 16; ++i){
        const bf16x8 af = mk8(hb[2 * i] & CLRM, hb[2 * i + 1] & CLRM);
#pragma unroll
        for(int g = 0; g < 4; ++g)
          acc[g] = __builtin_amdgcn_mfma_f32_16x16x32_bf16(af, whr[i][g], acc[g], 0, 0, 0);
      }
    }
    // epilogue: store h_t stamped into slot t
    u16* hn = hdX + (size_t)t * (NB * NH);
#pragma unroll
    for(int r = 0; r < 4; ++r){
      const float gi = acc[0][r] + bias[0];
      const float gf = acc[1][r] + bias[1];
      const float gg = acc[2][r] + bias[2];
      const float go = acc[3][r] + bias[3];
      creg[r] = sigm(gf) * creg[r] + sigm(gi) * tanh_(gg);
      const u32 stv  = (u32)f2bf(sigm(go) * tanh_(creg[r])) | 0x4000u;
      const u32 pair = stv | (((u32)__shfl_xor((int)stv, 1, 64)) << 16);
      const u32 hi   = (u32)__shfl_xor((int)pair, 2, 64);
      if((col & 3) == 0){
        const int row = btile * 16 + quad * 4 + r;
        ast64((u64*)(hn + (size_t)row * NH + mtile * 16 + col),
              (u64)pair | ((u64)hi << 32));
      }
    }
  }
}

// ---------------------------------------------------------------------------
// Decoder attention: 4096 FULLY PARALLEL blocks (one per (t, b)), 256
// threads. Reads h_t[b] (stamped bf16; kernel-boundary ordered), computes
// u = h @ W2^T + b2, scores over L with tanh, in-register log-softmax,
// writes out column (.., b, t). Saturates the chip.
// ---------------------------------------------------------------------------
__global__ void __launch_bounds__(256, 4) dec_attn_kernel(
    const float* __restrict__ W2, const float* __restrict__ b2,
    const float* __restrict__ vt, const float* __restrict__ vtb,
    const u16* __restrict__ bl,  const u16* __restrict__ hdX,
    float* __restrict__ out)
{
  __shared__ float h_f[NH];
  __shared__ float u_lds[NW];
  __shared__ float vt_lds[NW];
  __shared__ float red[8];

  const int tid  = threadIdx.x;
  const int lane = tid & 63;
  const int wvl  = tid >> 6;
  const int t = blockIdx.x >> 6;
  const int b = blockIdx.x & 63;

  // stage h_t[b] (stamped bf16) -> fp32 LDS
  {
    const u32 v = *(const u32*)(hdX + (size_t)t * (NB * NH) + (size_t)b * NH + 2 * tid);
    h_f[2 * tid]     = bf2f((u16)(v & 0xBFFFu));
    h_f[2 * tid + 1] = bf2f((u16)((v >> 16) & 0xBFFFu));
  }
  vt_lds[tid] = vt[tid];
  __syncthreads();

  // u[n] = b2[n] + h . W2[n,:]   (h broadcast from LDS)
  {
    const float* w2r = W2 + (size_t)tid * NH;
    float s = b2[tid];
#pragma unroll 8
    for(int k = 0; k < NH; ++k) s += h_f[k] * w2r[k];
    u_lds[tid] = s;
  }
  __syncthreads();

  // scores for l = tid and l = tid+256
  const float vtbf = vtb[0];
  float a0, a1;
#pragma unroll
  for(int e = 0; e < 2; ++e){
    const int l = tid + e * 256;
    const u16* br = bl + (size_t)(l * NB + b) * NW;
    float p = 0.f;
#pragma unroll 4
    for(int w = 0; w < NW; ++w)
      p += vt_lds[w] * tanh_(bf2f(br[w]) + u_lds[w]);
    if(e == 0) a0 = p + vtbf; else a1 = p + vtbf;
  }

  // log-softmax over L = 512 (2 values per thread, block-wide reduction)
  float mx = fmaxf(a0, a1);
#pragma unroll
  for(int off = 32; off > 0; off >>= 1) mx = fmaxf(mx, __shfl_xor(mx, off, 64));
  if(lane == 0) red[wvl] = mx;
  __syncthreads();
  mx = fmaxf(fmaxf(red[0], red[1]), fmaxf(red[2], red[3]));
  float es = __expf(a0 - mx) + __expf(a1 - mx);
#pragma unroll
  for(int off = 32; off > 0; off >>= 1) es += __shfl_xor(es, off, 64);
  if(lane == 0) red[4 + wvl] = es;
  __syncthreads();
  const float lse = mx + logf(red[4] + red[5] + red[6] + red[7]);
  out[((size_t)tid * NB + b) * NT + t]         = a0 - lse;
  out[((size_t)(tid + 256) * NB + b) * NT + t] = a1 - lse;
}

// ---------------------------------------------------------------------------
extern "C" void kernel_launch(void* const* d_in, const int* in_sizes, int n_in,
                              void* d_out, int out_size, void* d_ws, size_t ws_size,
                              hipStream_t stream)
{
  (void)in_sizes; (void)n_in; (void)out_size; (void)ws_size;
  const int*   ids  = (const int*)d_in[0];
  const float* emb  = (const float*)d_in[1];
  const float* eWih = (const float*)d_in[2];
  const float* eWhh = (const float*)d_in[3];
  const float* ebih = (const float*)d_in[4];
  const float* ebhh = (const float*)d_in[5];
  /* d_in[6] = dec_Wih: unused (decoder input is identically zero) */
  const float* dWhh = (const float*)d_in[7];
  const float* dbih = (const float*)d_in[8];
  const float* dbhh = (const float*)d_in[9];
  const float* W1   = (const float*)d_in[10];
  const float* b1   = (const float*)d_in[11];
  const float* W2   = (const float*)d_in[12];
  const float* b2   = (const float*)d_in[13];
  const float* vt   = (const float*)d_in[14];
  const float* vtb  = (const float*)d_in[15];
  const float* h0   = (const float*)d_in[16];

  // workspace: ~27.5 MB. Region X is bf16-emb during enc, then re-used as the
  // decoder's 64 write-once h slots (stamp bit14 disambiguates).
  char* ws = (char*)d_ws;
  u16* bl     = (u16*)ws; ws += (size_t)NL * NB * NW * 2;    // blend1 bf16  16.78 MB
  u16* hroll  = (u16*)ws; ws += (size_t)2 * NB * NH * 2;     // enc h ring   0.13 MB
  u16* X      = (u16*)ws; ws += (size_t)10000 * NE * 2;      // emb_b / hdec 5.12 MB
  u16* eWih_b = (u16*)ws; ws += (size_t)4 * NH * NE * 2;     // 1.05 MB
  u16* eWhh_b = (u16*)ws; ws += (size_t)4 * NH * NH * 2;     // 2.10 MB
  u16* dWhh_b = (u16*)ws; ws += (size_t)4 * NH * NH * 2;     // 2.10 MB
  u16* W1_b   = (u16*)ws; ws += (size_t)NW * NH * 2;         // 0.26 MB

  // enc ring slots pre-filled with stamp-1 pattern (first writes use stamp 0)
  hipLaunchKernelGGL(fill_kernel, dim3((2 * NB * NH / 2) / 256), dim3(256), 0, stream,
                     (u32*)hroll, 0x40004000u);
  hipLaunchKernelGGL(cvt_kernel, dim3(10000), dim3(256), 0, stream, emb,  X,      10000 * NE);
  hipLaunchKernelGGL(cvt_kernel, dim3(2048),  dim3(256), 0, stream, eWih, eWih_b, 4 * NH * NE);
  hipLaunchKernelGGL(cvt_kernel, dim3(4096),  dim3(256), 0, stream, eWhh, eWhh_b, 4 * NH * NH);
  hipLaunchKernelGGL(cvt_kernel, dim3(4096),  dim3(256), 0, stream, dWhh, dWhh_b, 4 * NH * NH);
  hipLaunchKernelGGL(cvt_kernel, dim3(512),   dim3(256), 0, stream, W1,   W1_b,   NW * NH);

  hipLaunchKernelGGL(enc_kernel, dim3(32), dim3(256), 0, stream,
                     ids, X, eWih_b, eWhh_b, ebih, ebhh, W1_b, b1, hroll, bl);
  hipLaunchKernelGGL(dec_lstm_kernel, dim3(32), dim3(256), 0, stream,
                     dWhh_b, dbih, dbhh, hroll, h0, X);
  hipLaunchKernelGGL(dec_attn_kernel, dim3(NT * NB), dim3(256), 0, stream,
                     W2, b2, vt, vtb, bl, X, (float*)d_out);
}